// Round 1
// baseline (2580.273 us; speedup 1.0000x reference)
//
#include <hip/hip_runtime.h>
#include <math.h>

#define NN 100000
#define EE 800000
#define ET (EE + NN)
#define BS 256

static inline int cdiv(long a, int b){ return (int)((a + b - 1) / b); }

// monotone float<->uint mapping for atomicMax on floats
__device__ __forceinline__ unsigned fmap(float f){
    unsigned b = __float_as_uint(f);
    return (b & 0x80000000u) ? ~b : (b | 0x80000000u);
}
__device__ __forceinline__ float funmap(unsigned u){
    unsigned b = (u & 0x80000000u) ? (u ^ 0x80000000u) : ~u;
    return __uint_as_float(b);
}

__global__ void k_zero_i32(int* p, int n){
    int i = blockIdx.x * BS + threadIdx.x;
    if (i < n) p[i] = 0;
}

__global__ void k_deg(const int* __restrict__ ei, int* __restrict__ deg){
    int e = blockIdx.x * BS + threadIdx.x;
    if (e >= ET) return;
    int d = (e < EE) ? ei[EE + e] : (e - EE);
    atomicAdd(&deg[d], 1);
}

// inclusive scan of deg: blockwise (256) -> block sums -> add offsets
__global__ void k_scan1(const int* __restrict__ deg, int* __restrict__ part,
                        int* __restrict__ bsum, int n){
    __shared__ int sh[BS];
    int i = blockIdx.x * BS + threadIdx.x;
    sh[threadIdx.x] = (i < n) ? deg[i] : 0;
    __syncthreads();
    for (int off = 1; off < BS; off <<= 1){
        int t = (threadIdx.x >= off) ? sh[threadIdx.x - off] : 0;
        __syncthreads();
        sh[threadIdx.x] += t;
        __syncthreads();
    }
    if (i < n) part[i] = sh[threadIdx.x];
    if (threadIdx.x == BS - 1) bsum[blockIdx.x] = sh[threadIdx.x];
}

__global__ void k_scan2(int* __restrict__ bsum, int nb){
    __shared__ int sh[512];
    int t = threadIdx.x;
    sh[t] = (t < nb) ? bsum[t] : 0;
    __syncthreads();
    for (int off = 1; off < 512; off <<= 1){
        int v = (t >= off) ? sh[t - off] : 0;
        __syncthreads();
        sh[t] += v;
        __syncthreads();
    }
    if (t < nb) bsum[t] = sh[t];
}

__global__ void k_scan3(const int* __restrict__ part, const int* __restrict__ bsum,
                        const int* __restrict__ deg, int* __restrict__ rowptr,
                        int* __restrict__ cursor, int n){
    int i = blockIdx.x * BS + threadIdx.x;
    if (i >= n) return;
    int blk = i >> 8;                       // matches SCAN block = 256
    int incl = part[i] + (blk ? bsum[blk - 1] : 0);
    int excl = incl - deg[i];
    rowptr[i] = excl;
    cursor[i] = excl;
    if (i == n - 1) rowptr[n] = incl;       // == ET
}

__global__ void k_fill(const int* __restrict__ ei, int* __restrict__ cursor,
                       int2* __restrict__ slots){
    int e = blockIdx.x * BS + threadIdx.x;
    if (e >= ET) return;
    int s, d;
    if (e < EE){ s = ei[e]; d = ei[EE + e]; } else { s = e - EE; d = s; }
    int pos = atomicAdd(&cursor[d], 1);
    slots[pos] = make_int2(s, e);
}

// H[n, M] = X[n, K] @ W[K, M]; thread per output element
__global__ void k_gemm(const float* __restrict__ X, const float* __restrict__ W,
                       float* __restrict__ H, int K, int M){
    int idx = blockIdx.x * BS + threadIdx.x;
    if (idx >= NN * M) return;
    int n = idx / M, m = idx - n * M;
    const float* x = X + (long)n * K;
    float acc = 0.f;
    #pragma unroll 4
    for (int k = 0; k < K; k++) acc = fmaf(x[k], W[k * M + m], acc);
    H[idx] = acc;
}

__global__ void k_alpha(const float* __restrict__ H, const float* __restrict__ as_,
                        const float* __restrict__ ad_, float* __restrict__ als,
                        float* __restrict__ ald, int Hh, int C){
    int idx = blockIdx.x * BS + threadIdx.x;
    if (idx >= NN * Hh) return;
    int n = idx / Hh, hd = idx - n * Hh;
    const float* hp = H + (long)n * Hh * C + hd * C;
    float s = 0.f, d = 0.f;
    for (int j = 0; j < C; j++){
        float v = hp[j];
        s = fmaf(v, as_[hd * C + j], s);
        d = fmaf(v, ad_[hd * C + j], d);
    }
    als[idx] = s;
    ald[idx] = d;
}

__global__ void k_init_mz(unsigned* __restrict__ m, float* __restrict__ z, int n){
    int i = blockIdx.x * BS + threadIdx.x;
    if (i < n){ m[i] = 0u; z[i] = 0.f; }    // 0 < fmap(any real); z accumulates from 0
}

__global__ void k_edge_max(const int* __restrict__ ei, const float* __restrict__ als,
                           const float* __restrict__ ald, float* __restrict__ el,
                           unsigned* __restrict__ m, int Hh){
    int idx = blockIdx.x * BS + threadIdx.x;
    if (idx >= ET * Hh) return;
    int e = idx / Hh, hd = idx - e * Hh;
    int s, d;
    if (e < EE){ s = ei[e]; d = ei[EE + e]; } else { s = e - EE; d = s; }
    float v = als[s * Hh + hd] + ald[d * Hh + hd];
    v = (v >= 0.f) ? v : 0.2f * v;          // leaky_relu, slope 0.2
    el[idx] = v;
    atomicMax(&m[d * Hh + hd], fmap(v));
}

__global__ void k_edge_exp(const int* __restrict__ ei, float* __restrict__ el,
                           const unsigned* __restrict__ m, float* __restrict__ z, int Hh){
    int idx = blockIdx.x * BS + threadIdx.x;
    if (idx >= ET * Hh) return;
    int e = idx / Hh, hd = idx - e * Hh;
    int d = (e < EE) ? ei[EE + e] : (e - EE);
    float ex = expf(el[idx] - funmap(m[d * Hh + hd]));
    el[idx] = ex;
    atomicAdd(&z[d * Hh + hd], ex);
}

// out[n, j] = relu( (sum over in-edges ex[e,hd] * H[src, j]) / z[n,hd] + b[j] )
__global__ void k_agg(const float* __restrict__ H, const float* __restrict__ ex,
                      const float* __restrict__ z, const int* __restrict__ rowptr,
                      const int2* __restrict__ slots, const float* __restrict__ b,
                      float* __restrict__ out, int Hh, int C){
    int M = Hh * C;
    int idx = blockIdx.x * BS + threadIdx.x;
    if (idx >= NN * M) return;
    int n = idx / M, j = idx - n * M;
    int hd = j / C;
    float acc = 0.f;
    int beg = rowptr[n], end = rowptr[n + 1];
    for (int p = beg; p < end; p++){
        int2 sl = slots[p];
        acc = fmaf(ex[sl.y * Hh + hd], H[sl.x * M + j], acc);
    }
    float o = acc / z[n * Hh + hd] + b[j];
    out[idx] = (o > 0.f) ? o : 0.f;
}

extern "C" void kernel_launch(void* const* d_in, const int* in_sizes, int n_in,
                              void* d_out, int out_size, void* d_ws, size_t ws_size,
                              hipStream_t stream){
    const float* x0 = (const float*)d_in[0];
    const int*   ei = (const int*)d_in[1];
    // d_in[2] = edge_attr: unused by the reference
    const float *W[5], *bia[5], *as_[5], *ad_[5];
    for (int i = 0; i < 5; i++){
        W[i]   = (const float*)d_in[3 + 4 * i];
        bia[i] = (const float*)d_in[4 + 4 * i];
        as_[i] = (const float*)d_in[5 + 4 * i];
        ad_[i] = (const float*)d_in[6 + 4 * i];
    }

    char* p = (char*)d_ws;
    auto alloc = [&](size_t bytes) -> char* {
        char* r = p;
        p += (bytes + 255) & ~(size_t)255;
        return r;
    };
    float*    Hbuf   = (float*)alloc((size_t)NN * 240 * 4);
    float*    Xbuf   = (float*)alloc((size_t)NN * 240 * 4);
    float*    el     = (float*)alloc((size_t)ET * 10 * 4);
    float*    als    = (float*)alloc((size_t)NN * 10 * 4);
    float*    ald    = (float*)alloc((size_t)NN * 10 * 4);
    unsigned* mm     = (unsigned*)alloc((size_t)NN * 10 * 4);
    float*    zz     = (float*)alloc((size_t)NN * 10 * 4);
    int*      deg    = (int*)alloc((size_t)NN * 4);
    int*      part   = (int*)alloc((size_t)NN * 4);
    int*      bsum   = (int*)alloc(512 * 4);
    int*      rowptr = (int*)alloc((size_t)(NN + 1) * 4);
    int*      cursor = (int*)alloc((size_t)NN * 4);
    int2*     slots  = (int2*)alloc((size_t)ET * 8);

    // ---- CSR build (dst-indexed), once per call ----
    k_zero_i32<<<cdiv(NN, BS), BS, 0, stream>>>(deg, NN);
    k_deg<<<cdiv(ET, BS), BS, 0, stream>>>(ei, deg);
    int nb = cdiv(NN, BS);                      // 391 <= 512
    k_scan1<<<nb, BS, 0, stream>>>(deg, part, bsum, NN);
    k_scan2<<<1, 512, 0, stream>>>(bsum, nb);
    k_scan3<<<cdiv(NN, BS), BS, 0, stream>>>(part, bsum, deg, rowptr, cursor, NN);
    k_fill<<<cdiv(ET, BS), BS, 0, stream>>>(ei, cursor, slots);

    // ---- 5 GAT layers ----
    const int Ks[5] = {32, 240, 120, 48, 24};
    const int Cs[5] = {24, 24, 24, 24, 12};
    const int Hs[5] = {10, 5, 2, 1, 1};
    const float* X = x0;
    for (int i = 0; i < 5; i++){
        int K = Ks[i], C = Cs[i], Hh = Hs[i], M = Hh * C;
        k_gemm<<<cdiv((long)NN * M, BS), BS, 0, stream>>>(X, W[i], Hbuf, K, M);
        k_alpha<<<cdiv((long)NN * Hh, BS), BS, 0, stream>>>(Hbuf, as_[i], ad_[i], als, ald, Hh, C);
        k_init_mz<<<cdiv(NN * Hh, BS), BS, 0, stream>>>(mm, zz, NN * Hh);
        k_edge_max<<<cdiv((long)ET * Hh, BS), BS, 0, stream>>>(ei, als, ald, el, mm, Hh);
        k_edge_exp<<<cdiv((long)ET * Hh, BS), BS, 0, stream>>>(ei, el, mm, zz, Hh);
        float* out = (i == 4) ? (float*)d_out : Xbuf;
        k_agg<<<cdiv((long)NN * M, BS), BS, 0, stream>>>(Hbuf, el, zz, rowptr, slots, bia[i], out, Hh, C);
        X = Xbuf;   // out of layer i (written into Xbuf) is next layer's input
    }
}

// Round 2
// 1816.772 us; speedup vs baseline: 1.4203x; 1.4203x over previous
//
#include <hip/hip_runtime.h>
#include <math.h>

#define NN 100000
#define EE 800000
#define ET (EE + NN)
#define BS 256

// GEMM tiling
#define BM 64
#define BN 64
#define BK 16

static inline int cdiv(long a, int b){ return (int)((a + b - 1) / b); }

// monotone float<->uint mapping for atomicMax on floats
__device__ __forceinline__ unsigned fmap(float f){
    unsigned b = __float_as_uint(f);
    return (b & 0x80000000u) ? ~b : (b | 0x80000000u);
}
__device__ __forceinline__ float funmap(unsigned u){
    unsigned b = (u & 0x80000000u) ? (u ^ 0x80000000u) : ~u;
    return __uint_as_float(b);
}

__global__ void k_zero_i32(int* p, int n){
    int i = blockIdx.x * BS + threadIdx.x;
    if (i < n) p[i] = 0;
}

__global__ void k_deg(const int* __restrict__ ei, int* __restrict__ deg){
    int e = blockIdx.x * BS + threadIdx.x;
    if (e >= ET) return;
    int d = (e < EE) ? ei[EE + e] : (e - EE);
    atomicAdd(&deg[d], 1);
}

// inclusive scan of deg: blockwise (256) -> block sums -> add offsets
__global__ void k_scan1(const int* __restrict__ deg, int* __restrict__ part,
                        int* __restrict__ bsum, int n){
    __shared__ int sh[BS];
    int i = blockIdx.x * BS + threadIdx.x;
    sh[threadIdx.x] = (i < n) ? deg[i] : 0;
    __syncthreads();
    for (int off = 1; off < BS; off <<= 1){
        int t = (threadIdx.x >= off) ? sh[threadIdx.x - off] : 0;
        __syncthreads();
        sh[threadIdx.x] += t;
        __syncthreads();
    }
    if (i < n) part[i] = sh[threadIdx.x];
    if (threadIdx.x == BS - 1) bsum[blockIdx.x] = sh[threadIdx.x];
}

__global__ void k_scan2(int* __restrict__ bsum, int nb){
    __shared__ int sh[512];
    int t = threadIdx.x;
    sh[t] = (t < nb) ? bsum[t] : 0;
    __syncthreads();
    for (int off = 1; off < 512; off <<= 1){
        int v = (t >= off) ? sh[t - off] : 0;
        __syncthreads();
        sh[t] += v;
        __syncthreads();
    }
    if (t < nb) bsum[t] = sh[t];
}

__global__ void k_scan3(const int* __restrict__ part, const int* __restrict__ bsum,
                        const int* __restrict__ deg, int* __restrict__ rowptr,
                        int* __restrict__ cursor, int n){
    int i = blockIdx.x * BS + threadIdx.x;
    if (i >= n) return;
    int blk = i >> 8;                       // matches SCAN block = 256
    int incl = part[i] + (blk ? bsum[blk - 1] : 0);
    int excl = incl - deg[i];
    rowptr[i] = excl;
    cursor[i] = excl;
    if (i == n - 1) rowptr[n] = incl;       // == ET
}

__global__ void k_fill(const int* __restrict__ ei, int* __restrict__ cursor,
                       int2* __restrict__ slots){
    int e = blockIdx.x * BS + threadIdx.x;
    if (e >= ET) return;
    int s, d;
    if (e < EE){ s = ei[e]; d = ei[EE + e]; } else { s = e - EE; d = s; }
    int pos = atomicAdd(&cursor[d], 1);
    slots[pos] = make_int2(s, e);
}

// Tiled fp32 GEMM: H[n, M] = X[n, K] @ W[K, M].
// 64x64 block tile, BK=16, 16x16 thread grid, 4x4 micro-tile per thread.
// Xs stride 68 keeps float4 rows 16B-aligned and <=2-way bank aliasing (free).
__global__ __launch_bounds__(256) void k_gemm_t(const float* __restrict__ X,
                                                const float* __restrict__ W,
                                                float* __restrict__ H, int K, int M){
    __shared__ float Xs[BK][BM + 4];
    __shared__ float Ws[BK][BN];
    const int tx = threadIdx.x & 15;        // col group
    const int ty = threadIdx.x >> 4;        // row group
    const int n0 = blockIdx.x * BM;
    const int m0 = blockIdx.y * BN;
    const int lr = threadIdx.x >> 4;        // X-load: row 0..15 (+16*i)
    const int lk = threadIdx.x & 15;        // X-load: k within tile
    const int wk = threadIdx.x >> 6;        // W-load: k 0..3 (+4*i)
    const int wm = threadIdx.x & 63;        // W-load: col
    float acc[4][4] = {};

    for (int k0 = 0; k0 < K; k0 += BK){
        #pragma unroll
        for (int i = 0; i < 4; i++){
            int r = lr + 16 * i;
            int n = n0 + r;
            int k = k0 + lk;
            Xs[lk][r] = (n < NN && k < K) ? X[(long)n * K + k] : 0.f;
        }
        #pragma unroll
        for (int i = 0; i < 4; i++){
            int k = k0 + wk + 4 * i;
            Ws[wk + 4 * i][wm] = (k < K && m0 + wm < M) ? W[k * M + m0 + wm] : 0.f;
        }
        __syncthreads();
        #pragma unroll
        for (int kk = 0; kk < BK; kk++){
            float4 xv = *(const float4*)&Xs[kk][ty * 4];
            float4 wv = *(const float4*)&Ws[kk][tx * 4];
            acc[0][0] = fmaf(xv.x, wv.x, acc[0][0]);
            acc[0][1] = fmaf(xv.x, wv.y, acc[0][1]);
            acc[0][2] = fmaf(xv.x, wv.z, acc[0][2]);
            acc[0][3] = fmaf(xv.x, wv.w, acc[0][3]);
            acc[1][0] = fmaf(xv.y, wv.x, acc[1][0]);
            acc[1][1] = fmaf(xv.y, wv.y, acc[1][1]);
            acc[1][2] = fmaf(xv.y, wv.z, acc[1][2]);
            acc[1][3] = fmaf(xv.y, wv.w, acc[1][3]);
            acc[2][0] = fmaf(xv.z, wv.x, acc[2][0]);
            acc[2][1] = fmaf(xv.z, wv.y, acc[2][1]);
            acc[2][2] = fmaf(xv.z, wv.z, acc[2][2]);
            acc[2][3] = fmaf(xv.z, wv.w, acc[2][3]);
            acc[3][0] = fmaf(xv.w, wv.x, acc[3][0]);
            acc[3][1] = fmaf(xv.w, wv.y, acc[3][1]);
            acc[3][2] = fmaf(xv.w, wv.z, acc[3][2]);
            acc[3][3] = fmaf(xv.w, wv.w, acc[3][3]);
        }
        __syncthreads();
    }

    #pragma unroll
    for (int i = 0; i < 4; i++){
        int n = n0 + ty * 4 + i;
        if (n >= NN) break;
        #pragma unroll
        for (int j = 0; j < 4; j++){
            int m = m0 + tx * 4 + j;
            if (m < M) H[(long)n * M + m] = acc[i][j];
        }
    }
}

__global__ void k_alpha(const float* __restrict__ H, const float* __restrict__ as_,
                        const float* __restrict__ ad_, float* __restrict__ als,
                        float* __restrict__ ald, int Hh, int C){
    int idx = blockIdx.x * BS + threadIdx.x;
    if (idx >= NN * Hh) return;
    int n = idx / Hh, hd = idx - n * Hh;
    const float* hp = H + (long)n * Hh * C + hd * C;
    float s = 0.f, d = 0.f;
    for (int j = 0; j < C; j++){
        float v = hp[j];
        s = fmaf(v, as_[hd * C + j], s);
        d = fmaf(v, ad_[hd * C + j], d);
    }
    als[idx] = s;
    ald[idx] = d;
}

__global__ void k_init_mz(unsigned* __restrict__ m, float* __restrict__ z, int n){
    int i = blockIdx.x * BS + threadIdx.x;
    if (i < n){ m[i] = 0u; z[i] = 0.f; }    // 0 < fmap(any real); z accumulates from 0
}

__global__ void k_edge_max(const int* __restrict__ ei, const float* __restrict__ als,
                           const float* __restrict__ ald, float* __restrict__ el,
                           unsigned* __restrict__ m, int Hh){
    int idx = blockIdx.x * BS + threadIdx.x;
    if (idx >= ET * Hh) return;
    int e = idx / Hh, hd = idx - e * Hh;
    int s, d;
    if (e < EE){ s = ei[e]; d = ei[EE + e]; } else { s = e - EE; d = s; }
    float v = als[s * Hh + hd] + ald[d * Hh + hd];
    v = (v >= 0.f) ? v : 0.2f * v;          // leaky_relu, slope 0.2
    el[idx] = v;
    atomicMax(&m[d * Hh + hd], fmap(v));
}

__global__ void k_edge_exp(const int* __restrict__ ei, float* __restrict__ el,
                           const unsigned* __restrict__ m, float* __restrict__ z, int Hh){
    int idx = blockIdx.x * BS + threadIdx.x;
    if (idx >= ET * Hh) return;
    int e = idx / Hh, hd = idx - e * Hh;
    int d = (e < EE) ? ei[EE + e] : (e - EE);
    float ex = expf(el[idx] - funmap(m[d * Hh + hd]));
    el[idx] = ex;
    atomicAdd(&z[d * Hh + hd], ex);
}

// out[n, j] = relu( (sum over in-edges ex[e,hd] * H[src, j]) / z[n,hd] + b[j] )
__global__ void k_agg(const float* __restrict__ H, const float* __restrict__ ex,
                      const float* __restrict__ z, const int* __restrict__ rowptr,
                      const int2* __restrict__ slots, const float* __restrict__ b,
                      float* __restrict__ out, int Hh, int C){
    int M = Hh * C;
    int idx = blockIdx.x * BS + threadIdx.x;
    if (idx >= NN * M) return;
    int n = idx / M, j = idx - n * M;
    int hd = j / C;
    float acc = 0.f;
    int beg = rowptr[n], end = rowptr[n + 1];
    for (int p = beg; p < end; p++){
        int2 sl = slots[p];
        acc = fmaf(ex[sl.y * Hh + hd], H[sl.x * M + j], acc);
    }
    float o = acc / z[n * Hh + hd] + b[j];
    out[idx] = (o > 0.f) ? o : 0.f;
}

extern "C" void kernel_launch(void* const* d_in, const int* in_sizes, int n_in,
                              void* d_out, int out_size, void* d_ws, size_t ws_size,
                              hipStream_t stream){
    const float* x0 = (const float*)d_in[0];
    const int*   ei = (const int*)d_in[1];
    // d_in[2] = edge_attr: unused by the reference
    const float *W[5], *bia[5], *as_[5], *ad_[5];
    for (int i = 0; i < 5; i++){
        W[i]   = (const float*)d_in[3 + 4 * i];
        bia[i] = (const float*)d_in[4 + 4 * i];
        as_[i] = (const float*)d_in[5 + 4 * i];
        ad_[i] = (const float*)d_in[6 + 4 * i];
    }

    char* p = (char*)d_ws;
    auto alloc = [&](size_t bytes) -> char* {
        char* r = p;
        p += (bytes + 255) & ~(size_t)255;
        return r;
    };
    float*    Hbuf   = (float*)alloc((size_t)NN * 240 * 4);
    float*    Xbuf   = (float*)alloc((size_t)NN * 240 * 4);
    float*    el     = (float*)alloc((size_t)ET * 10 * 4);
    float*    als    = (float*)alloc((size_t)NN * 10 * 4);
    float*    ald    = (float*)alloc((size_t)NN * 10 * 4);
    unsigned* mm     = (unsigned*)alloc((size_t)NN * 10 * 4);
    float*    zz     = (float*)alloc((size_t)NN * 10 * 4);
    int*      deg    = (int*)alloc((size_t)NN * 4);
    int*      part   = (int*)alloc((size_t)NN * 4);
    int*      bsum   = (int*)alloc(512 * 4);
    int*      rowptr = (int*)alloc((size_t)(NN + 1) * 4);
    int*      cursor = (int*)alloc((size_t)NN * 4);
    int2*     slots  = (int2*)alloc((size_t)ET * 8);

    // ---- CSR build (dst-indexed), once per call ----
    k_zero_i32<<<cdiv(NN, BS), BS, 0, stream>>>(deg, NN);
    k_deg<<<cdiv(ET, BS), BS, 0, stream>>>(ei, deg);
    int nb = cdiv(NN, BS);                      // 391 <= 512
    k_scan1<<<nb, BS, 0, stream>>>(deg, part, bsum, NN);
    k_scan2<<<1, 512, 0, stream>>>(bsum, nb);
    k_scan3<<<cdiv(NN, BS), BS, 0, stream>>>(part, bsum, deg, rowptr, cursor, NN);
    k_fill<<<cdiv(ET, BS), BS, 0, stream>>>(ei, cursor, slots);

    // ---- 5 GAT layers ----
    const int Ks[5] = {32, 240, 120, 48, 24};
    const int Cs[5] = {24, 24, 24, 24, 12};
    const int Hs[5] = {10, 5, 2, 1, 1};
    const float* X = x0;
    for (int i = 0; i < 5; i++){
        int K = Ks[i], C = Cs[i], Hh = Hs[i], M = Hh * C;
        dim3 ggrid(cdiv(NN, BM), cdiv(M, BN));
        k_gemm_t<<<ggrid, 256, 0, stream>>>(X, W[i], Hbuf, K, M);
        k_alpha<<<cdiv((long)NN * Hh, BS), BS, 0, stream>>>(Hbuf, as_[i], ad_[i], als, ald, Hh, C);
        k_init_mz<<<cdiv(NN * Hh, BS), BS, 0, stream>>>(mm, zz, NN * Hh);
        k_edge_max<<<cdiv((long)ET * Hh, BS), BS, 0, stream>>>(ei, als, ald, el, mm, Hh);
        k_edge_exp<<<cdiv((long)ET * Hh, BS), BS, 0, stream>>>(ei, el, mm, zz, Hh);
        float* out = (i == 4) ? (float*)d_out : Xbuf;
        k_agg<<<cdiv((long)NN * M, BS), BS, 0, stream>>>(Hbuf, el, zz, rowptr, slots, bia[i], out, Hh, C);
        X = Xbuf;   // out of layer i (written into Xbuf) is next layer's input
    }
}

// Round 3
// 1044.773 us; speedup vs baseline: 2.4697x; 1.7389x over previous
//
#include <hip/hip_runtime.h>
#include <math.h>

#define NN 100000
#define EE 800000
#define ET (EE + NN)
#define BS 256

// GEMM tiling
#define BM 64
#define BN 64
#define BK 16

static inline int cdiv(long a, int b){ return (int)((a + b - 1) / b); }

__global__ void k_zero_i32(int* p, int n){
    int i = blockIdx.x * BS + threadIdx.x;
    if (i < n) p[i] = 0;
}

__global__ void k_deg(const int* __restrict__ ei, int* __restrict__ deg){
    int e = blockIdx.x * BS + threadIdx.x;
    if (e >= ET) return;
    int d = (e < EE) ? ei[EE + e] : (e - EE);
    atomicAdd(&deg[d], 1);
}

// inclusive scan of deg: blockwise (256) -> block sums -> add offsets
__global__ void k_scan1(const int* __restrict__ deg, int* __restrict__ part,
                        int* __restrict__ bsum, int n){
    __shared__ int sh[BS];
    int i = blockIdx.x * BS + threadIdx.x;
    sh[threadIdx.x] = (i < n) ? deg[i] : 0;
    __syncthreads();
    for (int off = 1; off < BS; off <<= 1){
        int t = (threadIdx.x >= off) ? sh[threadIdx.x - off] : 0;
        __syncthreads();
        sh[threadIdx.x] += t;
        __syncthreads();
    }
    if (i < n) part[i] = sh[threadIdx.x];
    if (threadIdx.x == BS - 1) bsum[blockIdx.x] = sh[threadIdx.x];
}

__global__ void k_scan2(int* __restrict__ bsum, int nb){
    __shared__ int sh[512];
    int t = threadIdx.x;
    sh[t] = (t < nb) ? bsum[t] : 0;
    __syncthreads();
    for (int off = 1; off < 512; off <<= 1){
        int v = (t >= off) ? sh[t - off] : 0;
        __syncthreads();
        sh[t] += v;
        __syncthreads();
    }
    if (t < nb) bsum[t] = sh[t];
}

__global__ void k_scan3(const int* __restrict__ part, const int* __restrict__ bsum,
                        const int* __restrict__ deg, int* __restrict__ rowptr,
                        int* __restrict__ cursor, int n){
    int i = blockIdx.x * BS + threadIdx.x;
    if (i >= n) return;
    int blk = i >> 8;
    int incl = part[i] + (blk ? bsum[blk - 1] : 0);
    int excl = incl - deg[i];
    rowptr[i] = excl;
    cursor[i] = excl;
    if (i == n - 1) rowptr[n] = incl;       // == ET
}

__global__ void k_fill(const int* __restrict__ ei, int* __restrict__ cursor,
                       int* __restrict__ ssrc){
    int e = blockIdx.x * BS + threadIdx.x;
    if (e >= ET) return;
    int s, d;
    if (e < EE){ s = ei[e]; d = ei[EE + e]; } else { s = e - EE; d = s; }
    int pos = atomicAdd(&cursor[d], 1);
    ssrc[pos] = s;
}

// Tiled fp32 GEMM: H[n, M] = X[n, K] @ W[K, M].
__global__ __launch_bounds__(256) void k_gemm_t(const float* __restrict__ X,
                                                const float* __restrict__ W,
                                                float* __restrict__ H, int K, int M){
    __shared__ float Xs[BK][BM + 4];
    __shared__ float Ws[BK][BN];
    const int tx = threadIdx.x & 15;
    const int ty = threadIdx.x >> 4;
    const int n0 = blockIdx.x * BM;
    const int m0 = blockIdx.y * BN;
    const int lr = threadIdx.x >> 4;
    const int lk = threadIdx.x & 15;
    const int wk = threadIdx.x >> 6;
    const int wm = threadIdx.x & 63;
    float acc[4][4] = {};

    for (int k0 = 0; k0 < K; k0 += BK){
        #pragma unroll
        for (int i = 0; i < 4; i++){
            int r = lr + 16 * i;
            int n = n0 + r;
            int k = k0 + lk;
            Xs[lk][r] = (n < NN && k < K) ? X[(long)n * K + k] : 0.f;
        }
        #pragma unroll
        for (int i = 0; i < 4; i++){
            int k = k0 + wk + 4 * i;
            Ws[wk + 4 * i][wm] = (k < K && m0 + wm < M) ? W[k * M + m0 + wm] : 0.f;
        }
        __syncthreads();
        #pragma unroll
        for (int kk = 0; kk < BK; kk++){
            float4 xv = *(const float4*)&Xs[kk][ty * 4];
            float4 wv = *(const float4*)&Ws[kk][tx * 4];
            acc[0][0] = fmaf(xv.x, wv.x, acc[0][0]);
            acc[0][1] = fmaf(xv.x, wv.y, acc[0][1]);
            acc[0][2] = fmaf(xv.x, wv.z, acc[0][2]);
            acc[0][3] = fmaf(xv.x, wv.w, acc[0][3]);
            acc[1][0] = fmaf(xv.y, wv.x, acc[1][0]);
            acc[1][1] = fmaf(xv.y, wv.y, acc[1][1]);
            acc[1][2] = fmaf(xv.y, wv.z, acc[1][2]);
            acc[1][3] = fmaf(xv.y, wv.w, acc[1][3]);
            acc[2][0] = fmaf(xv.z, wv.x, acc[2][0]);
            acc[2][1] = fmaf(xv.z, wv.y, acc[2][1]);
            acc[2][2] = fmaf(xv.z, wv.z, acc[2][2]);
            acc[2][3] = fmaf(xv.z, wv.w, acc[2][3]);
            acc[3][0] = fmaf(xv.w, wv.x, acc[3][0]);
            acc[3][1] = fmaf(xv.w, wv.y, acc[3][1]);
            acc[3][2] = fmaf(xv.w, wv.z, acc[3][2]);
            acc[3][3] = fmaf(xv.w, wv.w, acc[3][3]);
        }
        __syncthreads();
    }

    #pragma unroll
    for (int i = 0; i < 4; i++){
        int n = n0 + ty * 4 + i;
        if (n >= NN) break;
        #pragma unroll
        for (int j = 0; j < 4; j++){
            int m = m0 + tx * 4 + j;
            if (m < M) H[(long)n * M + m] = acc[i][j];
        }
    }
}

__global__ void k_alpha(const float* __restrict__ H, const float* __restrict__ as_,
                        const float* __restrict__ ad_, float* __restrict__ als,
                        float* __restrict__ ald, int Hh, int C){
    int idx = blockIdx.x * BS + threadIdx.x;
    if (idx >= NN * Hh) return;
    int n = idx / Hh, hd = idx - n * Hh;
    const float* hp = H + (long)n * Hh * C + hd * C;
    float s = 0.f, d = 0.f;
    for (int j = 0; j < C; j++){
        float v = hp[j];
        s = fmaf(v, as_[hd * C + j], s);
        d = fmaf(v, ad_[hd * C + j], d);
    }
    als[idx] = s;
    ald[idx] = d;
}

// Per (dst,head): walk CSR row twice over L2-resident als -> m, z. No atomics.
template<int HH>
__global__ void k_mz(const float* __restrict__ als, const float* __restrict__ ald,
                     const int* __restrict__ rowptr, const int* __restrict__ ssrc,
                     float* __restrict__ marr, float* __restrict__ zarr){
    int idx = blockIdx.x * BS + threadIdx.x;
    if (idx >= NN * HH) return;
    int n = idx / HH, hd = idx - n * HH;
    float adv = ald[idx];
    int beg = rowptr[n], end = rowptr[n + 1];
    float m = -1e30f;
    for (int p = beg; p < end; p++){
        float e = als[ssrc[p] * HH + hd] + adv;
        e = (e >= 0.f) ? e : 0.2f * e;
        m = fmaxf(m, e);
    }
    float z = 0.f;
    for (int p = beg; p < end; p++){
        float e = als[ssrc[p] * HH + hd] + adv;
        e = (e >= 0.f) ? e : 0.2f * e;
        z += expf(e - m);
    }
    marr[idx] = m;
    zarr[idx] = z;
}

// Fused softmax+aggregate: one thread per (node, 4 channels).
// out[n, j0..j0+3] = relu( (sum_e ex_e * H[src_e, j0..j0+3]) / z + b )
template<int HH, int CC>
__global__ __launch_bounds__(256) void k_agg_t(const float* __restrict__ H,
        const float* __restrict__ als, const float* __restrict__ ald,
        const float* __restrict__ marr, const float* __restrict__ zarr,
        const int* __restrict__ rowptr, const int* __restrict__ ssrc,
        const float* __restrict__ b, float* __restrict__ out){
    constexpr int M = HH * CC;
    constexpr int TPN = M / 4;
    int idx = blockIdx.x * 256 + threadIdx.x;
    if (idx >= NN * TPN) return;
    int n = idx / TPN;
    int q = idx - n * TPN;
    int j0 = q * 4;
    int hd = j0 / CC;

    float mv   = marr[n * HH + hd];
    float zinv = 1.f / zarr[n * HH + hd];
    float adv  = ald[n * HH + hd];
    int beg = rowptr[n], end = rowptr[n + 1];

    float4 acc = make_float4(0.f, 0.f, 0.f, 0.f);
    for (int p = beg; p < end; p++){
        int s = ssrc[p];
        float e = als[s * HH + hd] + adv;
        e = (e >= 0.f) ? e : 0.2f * e;
        float ex = expf(e - mv);
        float4 hv = *(const float4*)(H + (long)s * M + j0);
        acc.x = fmaf(ex, hv.x, acc.x);
        acc.y = fmaf(ex, hv.y, acc.y);
        acc.z = fmaf(ex, hv.z, acc.z);
        acc.w = fmaf(ex, hv.w, acc.w);
    }
    float4 bv = *(const float4*)(b + j0);
    float4 o;
    o.x = fmaf(acc.x, zinv, bv.x);
    o.y = fmaf(acc.y, zinv, bv.y);
    o.z = fmaf(acc.z, zinv, bv.z);
    o.w = fmaf(acc.w, zinv, bv.w);
    o.x = (o.x > 0.f) ? o.x : 0.f;
    o.y = (o.y > 0.f) ? o.y : 0.f;
    o.z = (o.z > 0.f) ? o.z : 0.f;
    o.w = (o.w > 0.f) ? o.w : 0.f;
    *(float4*)(out + (long)n * M + j0) = o;
}

template<int HH, int CC>
static void run_layer(const float* X, const float* Wm, const float* bia,
                      const float* as_, const float* ad_, float* Hbuf,
                      float* als, float* ald, float* marr, float* zarr,
                      const int* rowptr, const int* ssrc, float* out, int K,
                      hipStream_t stream){
    constexpr int M = HH * CC;
    constexpr int TPN = M / 4;
    dim3 g(cdiv(NN, BM), cdiv(M, BN));
    k_gemm_t<<<g, 256, 0, stream>>>(X, Wm, Hbuf, K, M);
    k_alpha<<<cdiv((long)NN * HH, BS), BS, 0, stream>>>(Hbuf, as_, ad_, als, ald, HH, CC);
    k_mz<HH><<<cdiv((long)NN * HH, BS), BS, 0, stream>>>(als, ald, rowptr, ssrc, marr, zarr);
    k_agg_t<HH, CC><<<cdiv((long)NN * TPN, 256), 256, 0, stream>>>(
        Hbuf, als, ald, marr, zarr, rowptr, ssrc, bia, out);
}

extern "C" void kernel_launch(void* const* d_in, const int* in_sizes, int n_in,
                              void* d_out, int out_size, void* d_ws, size_t ws_size,
                              hipStream_t stream){
    const float* x0 = (const float*)d_in[0];
    const int*   ei = (const int*)d_in[1];
    // d_in[2] = edge_attr: unused by the reference
    const float *W[5], *bia[5], *as_[5], *ad_[5];
    for (int i = 0; i < 5; i++){
        W[i]   = (const float*)d_in[3 + 4 * i];
        bia[i] = (const float*)d_in[4 + 4 * i];
        as_[i] = (const float*)d_in[5 + 4 * i];
        ad_[i] = (const float*)d_in[6 + 4 * i];
    }

    char* p = (char*)d_ws;
    auto alloc = [&](size_t bytes) -> char* {
        char* r = p;
        p += (bytes + 255) & ~(size_t)255;
        return r;
    };
    float* Hbuf   = (float*)alloc((size_t)NN * 240 * 4);
    float* Xbuf   = (float*)alloc((size_t)NN * 240 * 4);
    float* als    = (float*)alloc((size_t)NN * 10 * 4);
    float* ald    = (float*)alloc((size_t)NN * 10 * 4);
    float* marr   = (float*)alloc((size_t)NN * 10 * 4);
    float* zarr   = (float*)alloc((size_t)NN * 10 * 4);
    int*   deg    = (int*)alloc((size_t)NN * 4);
    int*   part   = (int*)alloc((size_t)NN * 4);
    int*   bsum   = (int*)alloc(512 * 4);
    int*   rowptr = (int*)alloc((size_t)(NN + 1) * 4);
    int*   cursor = (int*)alloc((size_t)NN * 4);
    int*   ssrc   = (int*)alloc((size_t)ET * 4);

    // ---- CSR build (dst-indexed), once per call ----
    k_zero_i32<<<cdiv(NN, BS), BS, 0, stream>>>(deg, NN);
    k_deg<<<cdiv(ET, BS), BS, 0, stream>>>(ei, deg);
    int nb = cdiv(NN, BS);                      // 391 <= 512
    k_scan1<<<nb, BS, 0, stream>>>(deg, part, bsum, NN);
    k_scan2<<<1, 512, 0, stream>>>(bsum, nb);
    k_scan3<<<cdiv(NN, BS), BS, 0, stream>>>(part, bsum, deg, rowptr, cursor, NN);
    k_fill<<<cdiv(ET, BS), BS, 0, stream>>>(ei, cursor, ssrc);

    // ---- 5 GAT layers ----
    run_layer<10, 24>(x0,   W[0], bia[0], as_[0], ad_[0], Hbuf, als, ald, marr, zarr,
                      rowptr, ssrc, Xbuf, 32, stream);
    run_layer<5, 24>(Xbuf,  W[1], bia[1], as_[1], ad_[1], Hbuf, als, ald, marr, zarr,
                      rowptr, ssrc, Xbuf, 240, stream);
    run_layer<2, 24>(Xbuf,  W[2], bia[2], as_[2], ad_[2], Hbuf, als, ald, marr, zarr,
                      rowptr, ssrc, Xbuf, 120, stream);
    run_layer<1, 24>(Xbuf,  W[3], bia[3], as_[3], ad_[3], Hbuf, als, ald, marr, zarr,
                      rowptr, ssrc, Xbuf, 48, stream);
    run_layer<1, 12>(Xbuf,  W[4], bia[4], as_[4], ad_[4], Hbuf, als, ald, marr, zarr,
                      rowptr, ssrc, (float*)d_out, 24, stream);
}

// Round 4
// 812.517 us; speedup vs baseline: 3.1757x; 1.2858x over previous
//
#include <hip/hip_runtime.h>
#include <math.h>

#define NN 100000
#define EE 800000
#define ET (EE + NN)
#define BS 256

// GEMM tiling
#define BM 64
#define BN 64
#define BK 16

typedef _Float16 f16;
typedef __attribute__((ext_vector_type(4))) _Float16 half4;
typedef __attribute__((ext_vector_type(8))) _Float16 half8;
template<int V> struct HV;
template<> struct HV<4>{ typedef half4 type; };
template<> struct HV<8>{ typedef half8 type; };

static inline int cdiv(long a, int b){ return (int)((a + b - 1) / b); }

__global__ void k_zero_i32(int* p, int n){
    int i = blockIdx.x * BS + threadIdx.x;
    if (i < n) p[i] = 0;
}

__global__ void k_deg(const int* __restrict__ ei, int* __restrict__ deg){
    int e = blockIdx.x * BS + threadIdx.x;
    if (e >= ET) return;
    int d = (e < EE) ? ei[EE + e] : (e - EE);
    atomicAdd(&deg[d], 1);
}

// inclusive scan of deg: blockwise (256) -> block sums -> add offsets
__global__ void k_scan1(const int* __restrict__ deg, int* __restrict__ part,
                        int* __restrict__ bsum, int n){
    __shared__ int sh[BS];
    int i = blockIdx.x * BS + threadIdx.x;
    sh[threadIdx.x] = (i < n) ? deg[i] : 0;
    __syncthreads();
    for (int off = 1; off < BS; off <<= 1){
        int t = (threadIdx.x >= off) ? sh[threadIdx.x - off] : 0;
        __syncthreads();
        sh[threadIdx.x] += t;
        __syncthreads();
    }
    if (i < n) part[i] = sh[threadIdx.x];
    if (threadIdx.x == BS - 1) bsum[blockIdx.x] = sh[threadIdx.x];
}

__global__ void k_scan2(int* __restrict__ bsum, int nb){
    __shared__ int sh[512];
    int t = threadIdx.x;
    sh[t] = (t < nb) ? bsum[t] : 0;
    __syncthreads();
    for (int off = 1; off < 512; off <<= 1){
        int v = (t >= off) ? sh[t - off] : 0;
        __syncthreads();
        sh[t] += v;
        __syncthreads();
    }
    if (t < nb) bsum[t] = sh[t];
}

__global__ void k_scan3(const int* __restrict__ part, const int* __restrict__ bsum,
                        const int* __restrict__ deg, int* __restrict__ rowptr,
                        int* __restrict__ cursor, int n){
    int i = blockIdx.x * BS + threadIdx.x;
    if (i >= n) return;
    int blk = i >> 8;
    int incl = part[i] + (blk ? bsum[blk - 1] : 0);
    int excl = incl - deg[i];
    rowptr[i] = excl;
    cursor[i] = excl;
    if (i == n - 1) rowptr[n] = incl;       // == ET
}

__global__ void k_fill(const int* __restrict__ ei, int* __restrict__ cursor,
                       int* __restrict__ ssrc){
    int e = blockIdx.x * BS + threadIdx.x;
    if (e >= ET) return;
    int s, d;
    if (e < EE){ s = ei[e]; d = ei[EE + e]; } else { s = e - EE; d = s; }
    int pos = atomicAdd(&cursor[d], 1);
    ssrc[pos] = s;
}

// Fold attention vectors into W: Was[k,hd] = sum_c W[k, hd*C+c] * as[hd,c]
template<int HH, int CC>
__global__ void k_fold(const float* __restrict__ W, const float* __restrict__ as_,
                       const float* __restrict__ ad_, float* __restrict__ Was,
                       float* __restrict__ Wad, int K){
    int idx = blockIdx.x * 64 + threadIdx.x;
    if (idx >= K * HH) return;
    int k = idx / HH, hd = idx - k * HH;
    float s = 0.f, d = 0.f;
    #pragma unroll
    for (int c = 0; c < CC; c++){
        float w = W[k * (HH * CC) + hd * CC + c];
        s = fmaf(w, as_[hd * CC + c], s);
        d = fmaf(w, ad_[hd * CC + c], d);
    }
    Was[idx] = s;
    Wad[idx] = d;
}

// Tiled fp32 GEMM, fp16 output: H2[n, M] = (f16)(X[n, K] @ W[K, M]).
__global__ __launch_bounds__(256) void k_gemm_h(const float* __restrict__ X,
                                                const float* __restrict__ W,
                                                f16* __restrict__ H2, int K, int M){
    __shared__ float Xs[BK][BM + 4];
    __shared__ float Ws[BK][BN];
    const int tx = threadIdx.x & 15;
    const int ty = threadIdx.x >> 4;
    const int n0 = blockIdx.x * BM;
    const int m0 = blockIdx.y * BN;
    const int lr = threadIdx.x >> 4;
    const int lk = threadIdx.x & 15;
    const int wk = threadIdx.x >> 6;
    const int wm = threadIdx.x & 63;
    float acc[4][4] = {};

    for (int k0 = 0; k0 < K; k0 += BK){
        #pragma unroll
        for (int i = 0; i < 4; i++){
            int r = lr + 16 * i;
            int n = n0 + r;
            int k = k0 + lk;
            Xs[lk][r] = (n < NN && k < K) ? X[(long)n * K + k] : 0.f;
        }
        #pragma unroll
        for (int i = 0; i < 4; i++){
            int k = k0 + wk + 4 * i;
            Ws[wk + 4 * i][wm] = (k < K && m0 + wm < M) ? W[k * M + m0 + wm] : 0.f;
        }
        __syncthreads();
        #pragma unroll
        for (int kk = 0; kk < BK; kk++){
            float4 xv = *(const float4*)&Xs[kk][ty * 4];
            float4 wv = *(const float4*)&Ws[kk][tx * 4];
            acc[0][0] = fmaf(xv.x, wv.x, acc[0][0]);
            acc[0][1] = fmaf(xv.x, wv.y, acc[0][1]);
            acc[0][2] = fmaf(xv.x, wv.z, acc[0][2]);
            acc[0][3] = fmaf(xv.x, wv.w, acc[0][3]);
            acc[1][0] = fmaf(xv.y, wv.x, acc[1][0]);
            acc[1][1] = fmaf(xv.y, wv.y, acc[1][1]);
            acc[1][2] = fmaf(xv.y, wv.z, acc[1][2]);
            acc[1][3] = fmaf(xv.y, wv.w, acc[1][3]);
            acc[2][0] = fmaf(xv.z, wv.x, acc[2][0]);
            acc[2][1] = fmaf(xv.z, wv.y, acc[2][1]);
            acc[2][2] = fmaf(xv.z, wv.z, acc[2][2]);
            acc[2][3] = fmaf(xv.z, wv.w, acc[2][3]);
            acc[3][0] = fmaf(xv.w, wv.x, acc[3][0]);
            acc[3][1] = fmaf(xv.w, wv.y, acc[3][1]);
            acc[3][2] = fmaf(xv.w, wv.z, acc[3][2]);
            acc[3][3] = fmaf(xv.w, wv.w, acc[3][3]);
        }
        __syncthreads();
    }

    int m = m0 + tx * 4;
    if (m < M){                               // M % 4 == 0 -> whole chunk valid
        #pragma unroll
        for (int i = 0; i < 4; i++){
            int n = n0 + ty * 4 + i;
            if (n >= NN) break;
            half4 hv = { (f16)acc[i][0], (f16)acc[i][1], (f16)acc[i][2], (f16)acc[i][3] };
            *(half4*)(H2 + (long)n * M + m) = hv;
        }
    }
}

// als/ald in fp32 straight from X via folded weights (thread per node)
template<int HH>
__global__ void k_alpha2(const float* __restrict__ X, const float* __restrict__ Was,
                         const float* __restrict__ Wad, float* __restrict__ als,
                         float* __restrict__ ald, int K){
    int n = blockIdx.x * BS + threadIdx.x;
    if (n >= NN) return;
    float s[HH] = {}, d[HH] = {};
    const float* x = X + (long)n * K;
    for (int k = 0; k < K; k += 4){
        float4 xv = *(const float4*)(x + k);
        #pragma unroll
        for (int hd = 0; hd < HH; hd++){
            s[hd] = fmaf(xv.x, Was[(k + 0) * HH + hd], s[hd]);
            s[hd] = fmaf(xv.y, Was[(k + 1) * HH + hd], s[hd]);
            s[hd] = fmaf(xv.z, Was[(k + 2) * HH + hd], s[hd]);
            s[hd] = fmaf(xv.w, Was[(k + 3) * HH + hd], s[hd]);
            d[hd] = fmaf(xv.x, Wad[(k + 0) * HH + hd], d[hd]);
            d[hd] = fmaf(xv.y, Wad[(k + 1) * HH + hd], d[hd]);
            d[hd] = fmaf(xv.z, Wad[(k + 2) * HH + hd], d[hd]);
            d[hd] = fmaf(xv.w, Wad[(k + 3) * HH + hd], d[hd]);
        }
    }
    #pragma unroll
    for (int hd = 0; hd < HH; hd++){
        als[n * HH + hd] = s[hd];
        ald[n * HH + hd] = d[hd];
    }
}

// Per (dst,head): walk CSR row twice over L2-resident als -> m, z. No atomics.
template<int HH>
__global__ void k_mz(const float* __restrict__ als, const float* __restrict__ ald,
                     const int* __restrict__ rowptr, const int* __restrict__ ssrc,
                     float* __restrict__ marr, float* __restrict__ zarr){
    int idx = blockIdx.x * BS + threadIdx.x;
    if (idx >= NN * HH) return;
    int n = idx / HH, hd = idx - n * HH;
    float adv = ald[idx];
    int beg = rowptr[n], end = rowptr[n + 1];
    float m = -1e30f;
    for (int p = beg; p < end; p++){
        float e = als[ssrc[p] * HH + hd] + adv;
        e = (e >= 0.f) ? e : 0.2f * e;
        m = fmaxf(m, e);
    }
    float z = 0.f;
    for (int p = beg; p < end; p++){
        float e = als[ssrc[p] * HH + hd] + adv;
        e = (e >= 0.f) ? e : 0.2f * e;
        z += expf(e - m);
    }
    marr[idx] = m;
    zarr[idx] = z;
}

// Fused softmax+aggregate over fp16 H: one thread per (node, VEC channels).
template<int HH, int CC, int VEC>
__global__ __launch_bounds__(256) void k_agg_h(const f16* __restrict__ H2,
        const float* __restrict__ als, const float* __restrict__ ald,
        const float* __restrict__ marr, const float* __restrict__ zarr,
        const int* __restrict__ rowptr, const int* __restrict__ ssrc,
        const float* __restrict__ b, float* __restrict__ out){
    constexpr int M = HH * CC;
    constexpr int TPN = M / VEC;
    typedef typename HV<VEC>::type hvec;
    int idx = blockIdx.x * 256 + threadIdx.x;
    if (idx >= NN * TPN) return;
    int n = idx / TPN;
    int q = idx - n * TPN;
    int j0 = q * VEC;
    int hd = j0 / CC;

    float mv   = marr[n * HH + hd];
    float zinv = 1.f / zarr[n * HH + hd];
    float adv  = ald[n * HH + hd];
    int beg = rowptr[n], end = rowptr[n + 1];

    float acc[VEC] = {};
    for (int p = beg; p < end; p++){
        int s = ssrc[p];
        float e = als[s * HH + hd] + adv;
        e = (e >= 0.f) ? e : 0.2f * e;
        float ex = expf(e - mv);
        hvec hv = *(const hvec*)(H2 + (long)s * M + j0);
        #pragma unroll
        for (int c = 0; c < VEC; c++)
            acc[c] = fmaf(ex, (float)hv[c], acc[c]);
    }
    #pragma unroll
    for (int c = 0; c < VEC; c++){
        float o = fmaf(acc[c], zinv, b[j0 + c]);
        out[(long)n * M + j0 + c] = (o > 0.f) ? o : 0.f;
    }
}

template<int HH, int CC, int VEC>
static void run_layer(const float* X, const float* Wm, const float* bia,
                      const float* as_, const float* ad_, f16* H2,
                      float* Was, float* Wad,
                      float* als, float* ald, float* marr, float* zarr,
                      const int* rowptr, const int* ssrc, float* out, int K,
                      hipStream_t stream){
    constexpr int M = HH * CC;
    constexpr int TPN = M / VEC;
    k_fold<HH, CC><<<cdiv(K * HH, 64), 64, 0, stream>>>(Wm, as_, ad_, Was, Wad, K);
    dim3 g(cdiv(NN, BM), cdiv(M, BN));
    k_gemm_h<<<g, 256, 0, stream>>>(X, Wm, H2, K, M);
    k_alpha2<HH><<<cdiv(NN, BS), BS, 0, stream>>>(X, Was, Wad, als, ald, K);
    k_mz<HH><<<cdiv((long)NN * HH, BS), BS, 0, stream>>>(als, ald, rowptr, ssrc, marr, zarr);
    k_agg_h<HH, CC, VEC><<<cdiv((long)NN * TPN, 256), 256, 0, stream>>>(
        H2, als, ald, marr, zarr, rowptr, ssrc, bia, out);
}

extern "C" void kernel_launch(void* const* d_in, const int* in_sizes, int n_in,
                              void* d_out, int out_size, void* d_ws, size_t ws_size,
                              hipStream_t stream){
    const float* x0 = (const float*)d_in[0];
    const int*   ei = (const int*)d_in[1];
    // d_in[2] = edge_attr: unused by the reference
    const float *W[5], *bia[5], *as_[5], *ad_[5];
    for (int i = 0; i < 5; i++){
        W[i]   = (const float*)d_in[3 + 4 * i];
        bia[i] = (const float*)d_in[4 + 4 * i];
        as_[i] = (const float*)d_in[5 + 4 * i];
        ad_[i] = (const float*)d_in[6 + 4 * i];
    }

    char* p = (char*)d_ws;
    auto alloc = [&](size_t bytes) -> char* {
        char* r = p;
        p += (bytes + 255) & ~(size_t)255;
        return r;
    };
    f16*   H2     = (f16*)alloc((size_t)NN * 240 * 2);
    float* Xbuf   = (float*)alloc((size_t)NN * 240 * 4);
    float* als    = (float*)alloc((size_t)NN * 10 * 4);
    float* ald    = (float*)alloc((size_t)NN * 10 * 4);
    float* marr   = (float*)alloc((size_t)NN * 10 * 4);
    float* zarr   = (float*)alloc((size_t)NN * 10 * 4);
    float* Was    = (float*)alloc((size_t)240 * 10 * 4);
    float* Wad    = (float*)alloc((size_t)240 * 10 * 4);
    int*   deg    = (int*)alloc((size_t)NN * 4);
    int*   part   = (int*)alloc((size_t)NN * 4);
    int*   bsum   = (int*)alloc(512 * 4);
    int*   rowptr = (int*)alloc((size_t)(NN + 1) * 4);
    int*   cursor = (int*)alloc((size_t)NN * 4);
    int*   ssrc   = (int*)alloc((size_t)ET * 4);

    // ---- CSR build (dst-indexed), once per call ----
    k_zero_i32<<<cdiv(NN, BS), BS, 0, stream>>>(deg, NN);
    k_deg<<<cdiv(ET, BS), BS, 0, stream>>>(ei, deg);
    int nb = cdiv(NN, BS);                      // 391 <= 512
    k_scan1<<<nb, BS, 0, stream>>>(deg, part, bsum, NN);
    k_scan2<<<1, 512, 0, stream>>>(bsum, nb);
    k_scan3<<<cdiv(NN, BS), BS, 0, stream>>>(part, bsum, deg, rowptr, cursor, NN);
    k_fill<<<cdiv(ET, BS), BS, 0, stream>>>(ei, cursor, ssrc);

    // ---- 5 GAT layers ----
    run_layer<10, 24, 8>(x0,  W[0], bia[0], as_[0], ad_[0], H2, Was, Wad, als, ald,
                         marr, zarr, rowptr, ssrc, Xbuf, 32, stream);
    run_layer<5, 24, 8>(Xbuf, W[1], bia[1], as_[1], ad_[1], H2, Was, Wad, als, ald,
                         marr, zarr, rowptr, ssrc, Xbuf, 240, stream);
    run_layer<2, 24, 8>(Xbuf, W[2], bia[2], as_[2], ad_[2], H2, Was, Wad, als, ald,
                         marr, zarr, rowptr, ssrc, Xbuf, 120, stream);
    run_layer<1, 24, 8>(Xbuf, W[3], bia[3], as_[3], ad_[3], H2, Was, Wad, als, ald,
                         marr, zarr, rowptr, ssrc, Xbuf, 48, stream);
    run_layer<1, 12, 4>(Xbuf, W[4], bia[4], as_[4], ad_[4], H2, Was, Wad, als, ald,
                         marr, zarr, rowptr, ssrc, (float*)d_out, 24, stream);
}

// Round 5
// 660.437 us; speedup vs baseline: 3.9069x; 1.2303x over previous
//
#include <hip/hip_runtime.h>
#include <math.h>

#define NN 100000
#define EE 800000
#define ET (EE + NN)
#define BS 256

typedef _Float16 f16;
typedef __attribute__((ext_vector_type(4))) _Float16 half4;
typedef __attribute__((ext_vector_type(8))) _Float16 half8;
typedef __attribute__((ext_vector_type(4))) float f32x4;
template<int V> struct HV;
template<> struct HV<4>{ typedef half4 type; };
template<> struct HV<8>{ typedef half8 type; };

static inline int cdiv(long a, int b){ return (int)((a + b - 1) / b); }

// ---------------- CSR build ----------------
__global__ void k_zero_i32(int* p, int n){
    int i = blockIdx.x * BS + threadIdx.x;
    if (i < n) p[i] = 0;
}

__global__ void k_deg(const int* __restrict__ ei, int* __restrict__ deg){
    int e = blockIdx.x * BS + threadIdx.x;
    if (e >= ET) return;
    int d = (e < EE) ? ei[EE + e] : (e - EE);
    atomicAdd(&deg[d], 1);
}

__global__ void k_scan1(const int* __restrict__ deg, int* __restrict__ part,
                        int* __restrict__ bsum, int n){
    __shared__ int sh[BS];
    int i = blockIdx.x * BS + threadIdx.x;
    sh[threadIdx.x] = (i < n) ? deg[i] : 0;
    __syncthreads();
    for (int off = 1; off < BS; off <<= 1){
        int t = (threadIdx.x >= off) ? sh[threadIdx.x - off] : 0;
        __syncthreads();
        sh[threadIdx.x] += t;
        __syncthreads();
    }
    if (i < n) part[i] = sh[threadIdx.x];
    if (threadIdx.x == BS - 1) bsum[blockIdx.x] = sh[threadIdx.x];
}

__global__ void k_scan2(int* __restrict__ bsum, int nb){
    __shared__ int sh[512];
    int t = threadIdx.x;
    sh[t] = (t < nb) ? bsum[t] : 0;
    __syncthreads();
    for (int off = 1; off < 512; off <<= 1){
        int v = (t >= off) ? sh[t - off] : 0;
        __syncthreads();
        sh[t] += v;
        __syncthreads();
    }
    if (t < nb) bsum[t] = sh[t];
}

__global__ void k_scan3(const int* __restrict__ part, const int* __restrict__ bsum,
                        const int* __restrict__ deg, int* __restrict__ rowptr,
                        int* __restrict__ cursor, int n){
    int i = blockIdx.x * BS + threadIdx.x;
    if (i >= n) return;
    int blk = i >> 8;
    int incl = part[i] + (blk ? bsum[blk - 1] : 0);
    int excl = incl - deg[i];
    rowptr[i] = excl;
    cursor[i] = excl;
    if (i == n - 1) rowptr[n] = incl;
}

__global__ void k_fill(const int* __restrict__ ei, int* __restrict__ cursor,
                       int* __restrict__ ssrc){
    int e = blockIdx.x * BS + threadIdx.x;
    if (e >= ET) return;
    int s, d;
    if (e < EE){ s = ei[e]; d = ei[EE + e]; } else { s = e - EE; d = s; }
    int pos = atomicAdd(&cursor[d], 1);
    ssrc[pos] = s;
}

// ---------------- per-layer prep: pack W to B-fragment layout + pad bias + fold alpha ----------------
// Wpk layout: idx = ((ks*NT + nt)*64 + lane)*8 + j  holds  W[k][n],
//   k = ks*32 + (lane>>4)*8 + j, n = nt*16 + (lane&15); zero-padded.
template<int K, int M, int KP, int MP, int HH, int CC>
__global__ void k_prep(const float* __restrict__ W, const float* __restrict__ b,
                       const float* __restrict__ as_, const float* __restrict__ ad_,
                       f16* __restrict__ Wpk, float* __restrict__ bp,
                       float* __restrict__ Was, float* __restrict__ Wad){
    constexpr int NT = MP / 16;
    int idx = blockIdx.x * 256 + threadIdx.x;
    if (idx < KP * MP){
        int j    = idx & 7;
        int lane = (idx >> 3) & 63;
        int rest = idx >> 9;                 // ks*NT + nt
        int nt   = rest % NT;
        int ks   = rest / NT;
        int k = ks * 32 + ((lane >> 4) & 3) * 8 + j;
        int n = nt * 16 + (lane & 15);
        Wpk[idx] = (k < K && n < M) ? (f16)W[k * M + n] : (f16)0.f;
    }
    if (idx < MP) bp[idx] = (idx < M) ? b[idx] : 0.f;
    if (idx < K * HH){
        int k = idx / HH, hd = idx - k * HH;
        float s = 0.f, d = 0.f;
        #pragma unroll
        for (int c = 0; c < CC; c++){
            float w = W[k * M + hd * CC + c];
            s = fmaf(w, as_[hd * CC + c], s);
            d = fmaf(w, ad_[hd * CC + c], d);
        }
        Was[idx] = s;
        Wad[idx] = d;
    }
}

// ---------------- MFMA GEMM: H2[NN,MP] = Xh[NN,KP] @ Wpk ----------------
// 4 waves/block, each wave: 2 m-tiles (32 rows), all MP columns. 128 rows/block.
template<int KP, int MP>
__global__ __launch_bounds__(256) void k_gemm_mfma(const f16* __restrict__ Xh,
        const f16* __restrict__ Wpk, f16* __restrict__ H2){
    constexpr int NT = MP / 16;
    constexpr int KS = KP / 32;
    const int wave = threadIdx.x >> 6;
    const int lane = threadIdx.x & 63;
    const int quad = lane >> 4;
    const int l16  = lane & 15;
    const long row0 = (long)blockIdx.x * 128 + wave * 32;

    f32x4 acc[2][NT];
    #pragma unroll
    for (int mt = 0; mt < 2; mt++)
        #pragma unroll
        for (int nt = 0; nt < NT; nt++)
            acc[mt][nt] = (f32x4){0.f, 0.f, 0.f, 0.f};

    const long r0 = row0 + l16;
    const long r1 = row0 + 16 + l16;
    const half8 hz = {};
    for (int ks = 0; ks < KS; ks++){
        const int kk = ks * 32 + quad * 8;
        half8 a0 = (r0 < NN) ? *(const half8*)(Xh + r0 * KP + kk) : hz;
        half8 a1 = (r1 < NN) ? *(const half8*)(Xh + r1 * KP + kk) : hz;
        const f16* wp = Wpk + ((long)ks * NT * 64 + lane) * 8;
        #pragma unroll
        for (int nt = 0; nt < NT; nt++){
            half8 bfr = *(const half8*)(wp + (long)nt * 512);
            acc[0][nt] = __builtin_amdgcn_mfma_f32_16x16x32_f16(a0, bfr, acc[0][nt], 0, 0, 0);
            acc[1][nt] = __builtin_amdgcn_mfma_f32_16x16x32_f16(a1, bfr, acc[1][nt], 0, 0, 0);
        }
    }
    // C/D layout: col = lane&15, row = quad*4 + reg  [m89/m91]
    #pragma unroll
    for (int mt = 0; mt < 2; mt++){
        #pragma unroll
        for (int reg = 0; reg < 4; reg++){
            long r = row0 + mt * 16 + quad * 4 + reg;
            if (r < NN){
                #pragma unroll
                for (int nt = 0; nt < NT; nt++)
                    H2[r * MP + nt * 16 + l16] = (f16)acc[mt][nt][reg];
            }
        }
    }
}

// ---------------- alpha logits (fp32 math from fp16 X) ----------------
template<int HH>
__global__ void k_alpha2(const f16* __restrict__ Xh, const float* __restrict__ Was,
                         const float* __restrict__ Wad, float* __restrict__ als,
                         float* __restrict__ ald, int K, int KP){
    int n = blockIdx.x * BS + threadIdx.x;
    if (n >= NN) return;
    float s[HH] = {}, d[HH] = {};
    const f16* x = Xh + (long)n * KP;
    for (int k = 0; k < K; k += 4){
        half4 xv = *(const half4*)(x + k);
        float xf0 = (float)xv[0], xf1 = (float)xv[1], xf2 = (float)xv[2], xf3 = (float)xv[3];
        #pragma unroll
        for (int hd = 0; hd < HH; hd++){
            s[hd] = fmaf(xf0, Was[(k + 0) * HH + hd], s[hd]);
            s[hd] = fmaf(xf1, Was[(k + 1) * HH + hd], s[hd]);
            s[hd] = fmaf(xf2, Was[(k + 2) * HH + hd], s[hd]);
            s[hd] = fmaf(xf3, Was[(k + 3) * HH + hd], s[hd]);
            d[hd] = fmaf(xf0, Wad[(k + 0) * HH + hd], d[hd]);
            d[hd] = fmaf(xf1, Wad[(k + 1) * HH + hd], d[hd]);
            d[hd] = fmaf(xf2, Wad[(k + 2) * HH + hd], d[hd]);
            d[hd] = fmaf(xf3, Wad[(k + 3) * HH + hd], d[hd]);
        }
    }
    #pragma unroll
    for (int hd = 0; hd < HH; hd++){
        als[n * HH + hd] = s[hd];
        ald[n * HH + hd] = d[hd];
    }
}

// ---------------- softmax m,z per (dst, head) ----------------
template<int HH>
__global__ void k_mz(const float* __restrict__ als, const float* __restrict__ ald,
                     const int* __restrict__ rowptr, const int* __restrict__ ssrc,
                     float* __restrict__ marr, float* __restrict__ zarr){
    int idx = blockIdx.x * BS + threadIdx.x;
    if (idx >= NN * HH) return;
    int n = idx / HH, hd = idx - n * HH;
    float adv = ald[idx];
    int beg = rowptr[n], end = rowptr[n + 1];
    float m = -1e30f;
    for (int p = beg; p < end; p++){
        float e = als[ssrc[p] * HH + hd] + adv;
        e = (e >= 0.f) ? e : 0.2f * e;
        m = fmaxf(m, e);
    }
    float z = 0.f;
    for (int p = beg; p < end; p++){
        float e = als[ssrc[p] * HH + hd] + adv;
        e = (e >= 0.f) ? e : 0.2f * e;
        z += expf(e - m);
    }
    marr[idx] = m;
    zarr[idx] = z;
}

// ---------------- fused softmax + aggregate ----------------
template<int HH, int CC, int MP, int VEC, bool O16>
__global__ __launch_bounds__(256) void k_agg_h(const f16* __restrict__ H2,
        const float* __restrict__ als, const float* __restrict__ ald,
        const float* __restrict__ marr, const float* __restrict__ zarr,
        const int* __restrict__ rowptr, const int* __restrict__ ssrc,
        const float* __restrict__ bp, f16* __restrict__ out16,
        float* __restrict__ out32, int MREAL){
    constexpr int TPN = MP / VEC;
    typedef typename HV<VEC>::type hvec;
    int idx = blockIdx.x * 256 + threadIdx.x;
    if (idx >= NN * TPN) return;
    int n = idx / TPN;
    int q = idx - n * TPN;
    int j0 = q * VEC;
    int hd = j0 / CC; if (hd > HH - 1) hd = HH - 1;   // pad cols: data is zero anyway

    float mv   = marr[n * HH + hd];
    float zinv = 1.f / zarr[n * HH + hd];
    float adv  = ald[n * HH + hd];
    int beg = rowptr[n], end = rowptr[n + 1];

    float acc[VEC] = {};
    for (int p = beg; p < end; p++){
        int s = ssrc[p];
        float e = als[s * HH + hd] + adv;
        e = (e >= 0.f) ? e : 0.2f * e;
        float ex = expf(e - mv);
        hvec hv = *(const hvec*)(H2 + (long)s * MP + j0);
        #pragma unroll
        for (int c = 0; c < VEC; c++)
            acc[c] = fmaf(ex, (float)hv[c], acc[c]);
    }
    if constexpr (O16){
        hvec o;
        #pragma unroll
        for (int c = 0; c < VEC; c++){
            float v = fmaf(acc[c], zinv, bp[j0 + c]);
            o[c] = (f16)((v > 0.f) ? v : 0.f);
        }
        *(hvec*)(out16 + (long)n * MP + j0) = o;
    } else {
        if (j0 < MREAL){
            #pragma unroll
            for (int c = 0; c < VEC; c++){
                float v = fmaf(acc[c], zinv, bp[j0 + c]);
                out32[(long)n * MREAL + j0 + c] = (v > 0.f) ? v : 0.f;
            }
        }
    }
}

// ---------------- X0 fp32 -> fp16 ----------------
__global__ void k_cvt0(const float* __restrict__ X, f16* __restrict__ Xh){
    long i = (long)blockIdx.x * BS + threadIdx.x;
    if (i >= (long)NN * 8) return;
    float4 v = *(const float4*)(X + i * 4);
    half4 h = { (f16)v.x, (f16)v.y, (f16)v.z, (f16)v.w };
    *(half4*)(Xh + i * 4) = h;
}

// ---------------- layer driver ----------------
template<int K, int M, int KP, int MP, int HH, int CC, int VEC, bool O16>
static void run_layer(const f16* Xh, const float* Wm, const float* bia,
                      const float* as_, const float* ad_, f16* H2,
                      f16* Wpk, float* bp, float* Was, float* Wad,
                      float* als, float* ald, float* marr, float* zarr,
                      const int* rowptr, const int* ssrc,
                      f16* Xnext, float* out32, hipStream_t stream){
    constexpr int TPN = MP / VEC;
    k_prep<K, M, KP, MP, HH, CC><<<cdiv(KP * MP, 256), 256, 0, stream>>>(
        Wm, bia, as_, ad_, Wpk, bp, Was, Wad);
    k_gemm_mfma<KP, MP><<<cdiv(NN, 128), 256, 0, stream>>>(Xh, Wpk, H2);
    k_alpha2<HH><<<cdiv(NN, BS), BS, 0, stream>>>(Xh, Was, Wad, als, ald, K, KP);
    k_mz<HH><<<cdiv((long)NN * HH, BS), BS, 0, stream>>>(als, ald, rowptr, ssrc, marr, zarr);
    k_agg_h<HH, CC, MP, VEC, O16><<<cdiv((long)NN * TPN, 256), 256, 0, stream>>>(
        H2, als, ald, marr, zarr, rowptr, ssrc, bp, Xnext, out32, M);
}

extern "C" void kernel_launch(void* const* d_in, const int* in_sizes, int n_in,
                              void* d_out, int out_size, void* d_ws, size_t ws_size,
                              hipStream_t stream){
    const float* x0 = (const float*)d_in[0];
    const int*   ei = (const int*)d_in[1];
    const float *W[5], *bia[5], *as_[5], *ad_[5];
    for (int i = 0; i < 5; i++){
        W[i]   = (const float*)d_in[3 + 4 * i];
        bia[i] = (const float*)d_in[4 + 4 * i];
        as_[i] = (const float*)d_in[5 + 4 * i];
        ad_[i] = (const float*)d_in[6 + 4 * i];
    }

    char* p = (char*)d_ws;
    auto alloc = [&](size_t bytes) -> char* {
        char* r = p;
        p += (bytes + 255) & ~(size_t)255;
        return r;
    };
    f16*   Xh     = (f16*)alloc((size_t)NN * 256 * 2);
    f16*   H2     = (f16*)alloc((size_t)NN * 256 * 2);
    float* als    = (float*)alloc((size_t)NN * 10 * 4);
    float* ald    = (float*)alloc((size_t)NN * 10 * 4);
    float* marr   = (float*)alloc((size_t)NN * 10 * 4);
    float* zarr   = (float*)alloc((size_t)NN * 10 * 4);
    f16*   Wpk    = (f16*)alloc((size_t)256 * 256 * 2);
    float* bp     = (float*)alloc(256 * 4);
    float* Was    = (float*)alloc((size_t)240 * 10 * 4);
    float* Wad    = (float*)alloc((size_t)240 * 10 * 4);
    int*   deg    = (int*)alloc((size_t)NN * 4);
    int*   part   = (int*)alloc((size_t)NN * 4);
    int*   bsum   = (int*)alloc(512 * 4);
    int*   rowptr = (int*)alloc((size_t)(NN + 1) * 4);
    int*   cursor = (int*)alloc((size_t)NN * 4);
    int*   ssrc   = (int*)alloc((size_t)ET * 4);

    // ---- CSR build (dst-indexed), once per call ----
    k_zero_i32<<<cdiv(NN, BS), BS, 0, stream>>>(deg, NN);
    k_deg<<<cdiv(ET, BS), BS, 0, stream>>>(ei, deg);
    int nb = cdiv(NN, BS);
    k_scan1<<<nb, BS, 0, stream>>>(deg, part, bsum, NN);
    k_scan2<<<1, 512, 0, stream>>>(bsum, nb);
    k_scan3<<<cdiv(NN, BS), BS, 0, stream>>>(part, bsum, deg, rowptr, cursor, NN);
    k_fill<<<cdiv(ET, BS), BS, 0, stream>>>(ei, cursor, ssrc);

    // ---- X0 -> fp16 ----
    k_cvt0<<<cdiv((long)NN * 8, BS), BS, 0, stream>>>(x0, Xh);

    // ---- 5 GAT layers (K,M real; KP,MP padded to x32/x16) ----
    //            K    M   KP   MP  HH  CC VEC O16
    run_layer< 32, 240,  32, 256, 10, 24, 8, true >(Xh, W[0], bia[0], as_[0], ad_[0], H2,
        Wpk, bp, Was, Wad, als, ald, marr, zarr, rowptr, ssrc, Xh, nullptr, stream);
    run_layer<240, 120, 256, 128,  5, 24, 8, true >(Xh, W[1], bia[1], as_[1], ad_[1], H2,
        Wpk, bp, Was, Wad, als, ald, marr, zarr, rowptr, ssrc, Xh, nullptr, stream);
    run_layer<120,  48, 128,  64,  2, 24, 8, true >(Xh, W[2], bia[2], as_[2], ad_[2], H2,
        Wpk, bp, Was, Wad, als, ald, marr, zarr, rowptr, ssrc, Xh, nullptr, stream);
    run_layer< 48,  24,  64,  32,  1, 24, 8, true >(Xh, W[3], bia[3], as_[3], ad_[3], H2,
        Wpk, bp, Was, Wad, als, ald, marr, zarr, rowptr, ssrc, Xh, nullptr, stream);
    run_layer< 24,  12,  32,  16,  1, 12, 4, false>(Xh, W[4], bia[4], as_[4], ad_[4], H2,
        Wpk, bp, Was, Wad, als, ald, marr, zarr, rowptr, ssrc, nullptr, (float*)d_out, stream);
}

// Round 6
// 578.943 us; speedup vs baseline: 4.4569x; 1.1408x over previous
//
#include <hip/hip_runtime.h>
#include <math.h>

#define NN 100000
#define EE 800000
#define ET (EE + NN)
#define BS 256

typedef _Float16 f16;
typedef __attribute__((ext_vector_type(4))) _Float16 half4;
typedef __attribute__((ext_vector_type(8))) _Float16 half8;
typedef __attribute__((ext_vector_type(4))) float f32x4;
template<int V> struct HV;
template<> struct HV<4>{ typedef half4 type; };
template<> struct HV<8>{ typedef half8 type; };

static inline int cdiv(long a, int b){ return (int)((a + b - 1) / b); }

// ---------------- CSR build ----------------
__global__ void k_zero_i32(int* p, int n){
    int i = blockIdx.x * BS + threadIdx.x;
    if (i < n) p[i] = 0;
}

__global__ void k_deg(const int* __restrict__ ei, int* __restrict__ deg){
    int e = blockIdx.x * BS + threadIdx.x;
    if (e >= ET) return;
    int d = (e < EE) ? ei[EE + e] : (e - EE);
    atomicAdd(&deg[d], 1);
}

__global__ void k_scan1(const int* __restrict__ deg, int* __restrict__ part,
                        int* __restrict__ bsum, int n){
    __shared__ int sh[BS];
    int i = blockIdx.x * BS + threadIdx.x;
    sh[threadIdx.x] = (i < n) ? deg[i] : 0;
    __syncthreads();
    for (int off = 1; off < BS; off <<= 1){
        int t = (threadIdx.x >= off) ? sh[threadIdx.x - off] : 0;
        __syncthreads();
        sh[threadIdx.x] += t;
        __syncthreads();
    }
    if (i < n) part[i] = sh[threadIdx.x];
    if (threadIdx.x == BS - 1) bsum[blockIdx.x] = sh[threadIdx.x];
}

__global__ void k_scan2(int* __restrict__ bsum, int nb){
    __shared__ int sh[512];
    int t = threadIdx.x;
    sh[t] = (t < nb) ? bsum[t] : 0;
    __syncthreads();
    for (int off = 1; off < 512; off <<= 1){
        int v = (t >= off) ? sh[t - off] : 0;
        __syncthreads();
        sh[t] += v;
        __syncthreads();
    }
    if (t < nb) bsum[t] = sh[t];
}

__global__ void k_scan3(const int* __restrict__ part, const int* __restrict__ bsum,
                        const int* __restrict__ deg, int* __restrict__ rowptr,
                        int* __restrict__ cursor, int n){
    int i = blockIdx.x * BS + threadIdx.x;
    if (i >= n) return;
    int blk = i >> 8;
    int incl = part[i] + (blk ? bsum[blk - 1] : 0);
    int excl = incl - deg[i];
    rowptr[i] = excl;
    cursor[i] = excl;
    if (i == n - 1) rowptr[n] = incl;
}

__global__ void k_fill(const int* __restrict__ ei, int* __restrict__ cursor,
                       int* __restrict__ ssrc){
    int e = blockIdx.x * BS + threadIdx.x;
    if (e >= ET) return;
    int s, d;
    if (e < EE){ s = ei[e]; d = ei[EE + e]; } else { s = e - EE; d = s; }
    int pos = atomicAdd(&cursor[d], 1);
    ssrc[pos] = s;
}

// ---------------- prep (all layers in one kernel) ----------------
// Wpk layout: idx = ((ks*NT + nt)*64 + lane)*8 + j holds W[k][n],
//   k = ks*32 + (lane>>4)*8 + j, n = nt*16 + (lane&15); zero-padded.
template<int K, int M, int KP, int MP, int HH, int CC>
__device__ __forceinline__ void prep_one(int idx, const float* __restrict__ W,
        const float* __restrict__ b, const float* __restrict__ as_,
        const float* __restrict__ ad_, f16* __restrict__ Wpk,
        float* __restrict__ bp, float* __restrict__ Was, float* __restrict__ Wad){
    constexpr int NT = MP / 16;
    if (idx < KP * MP){
        int j    = idx & 7;
        int lane = (idx >> 3) & 63;
        int rest = idx >> 9;                 // ks*NT + nt
        int nt   = rest % NT;
        int ks   = rest / NT;
        int k = ks * 32 + ((lane >> 4) & 3) * 8 + j;
        int n = nt * 16 + (lane & 15);
        Wpk[idx] = (k < K && n < M) ? (f16)W[k * M + n] : (f16)0.f;
    }
    if (idx < MP) bp[idx] = (idx < M) ? b[idx] : 0.f;
    if (idx < K * HH){
        int k = idx / HH, hd = idx - k * HH;
        float s = 0.f, d = 0.f;
        #pragma unroll
        for (int c = 0; c < CC; c++){
            float w = W[k * M + hd * CC + c];
            s = fmaf(w, as_[hd * CC + c], s);
            d = fmaf(w, ad_[hd * CC + c], d);
        }
        Was[idx] = s;
        Wad[idx] = d;
    }
}

struct PrepAll {
    const float *W[5], *b[5], *as[5], *ad[5];
    f16*   Wpk[5];
    float* bp[5];
    float* Was[5];
    float* Wad[5];
};

// work sizes (KP*MP): L0 32*240=7680, L1 256*128=32768, L2 128*64=8192,
// L3 64*32=2048, L4 32*16=512 -> boundaries 7680,40448,48640,50688,51200
__global__ void k_prep_all(PrepAll a){
    int idx = blockIdx.x * 256 + threadIdx.x;
    if (idx < 7680)
        prep_one< 32, 240,  32, 240, 10, 24>(idx,         a.W[0], a.b[0], a.as[0], a.ad[0], a.Wpk[0], a.bp[0], a.Was[0], a.Wad[0]);
    else if (idx < 40448)
        prep_one<240, 120, 256, 128,  5, 24>(idx - 7680,  a.W[1], a.b[1], a.as[1], a.ad[1], a.Wpk[1], a.bp[1], a.Was[1], a.Wad[1]);
    else if (idx < 48640)
        prep_one<120,  48, 128,  64,  2, 24>(idx - 40448, a.W[2], a.b[2], a.as[2], a.ad[2], a.Wpk[2], a.bp[2], a.Was[2], a.Wad[2]);
    else if (idx < 50688)
        prep_one< 48,  24,  64,  32,  1, 24>(idx - 48640, a.W[3], a.b[3], a.as[3], a.ad[3], a.Wpk[3], a.bp[3], a.Was[3], a.Wad[3]);
    else if (idx < 51200)
        prep_one< 24,  12,  32,  16,  1, 12>(idx - 50688, a.W[4], a.b[4], a.as[4], a.ad[4], a.Wpk[4], a.bp[4], a.Was[4], a.Wad[4]);
}

// ---------------- MFMA GEMM + fused alpha logits ----------------
// 4 waves/block, 128 rows/block. After the MFMA epilogue, threads 0..127
// compute the fp32 alpha logits for this block's rows (X is cache-hot).
template<int K, int KP, int MPH, int HH>
__global__ __launch_bounds__(256) void k_gemm_mfma(const f16* __restrict__ Xh,
        const f16* __restrict__ Wpk, f16* __restrict__ H2,
        const float* __restrict__ Was, const float* __restrict__ Wad,
        float* __restrict__ als, float* __restrict__ ald){
    constexpr int NT = MPH / 16;
    constexpr int KS = KP / 32;
    const int wave = threadIdx.x >> 6;
    const int lane = threadIdx.x & 63;
    const int quad = lane >> 4;
    const int l16  = lane & 15;
    const long row0 = (long)blockIdx.x * 128 + wave * 32;

    f32x4 acc[2][NT];
    #pragma unroll
    for (int mt = 0; mt < 2; mt++)
        #pragma unroll
        for (int nt = 0; nt < NT; nt++)
            acc[mt][nt] = (f32x4){0.f, 0.f, 0.f, 0.f};

    const long r0 = row0 + l16;
    const long r1 = row0 + 16 + l16;
    const half8 hz = {};
    for (int ks = 0; ks < KS; ks++){
        const int kk = ks * 32 + quad * 8;
        half8 a0 = (r0 < NN) ? *(const half8*)(Xh + r0 * KP + kk) : hz;
        half8 a1 = (r1 < NN) ? *(const half8*)(Xh + r1 * KP + kk) : hz;
        const f16* wp = Wpk + ((long)ks * NT * 64 + lane) * 8;
        #pragma unroll
        for (int nt = 0; nt < NT; nt++){
            half8 bfr = *(const half8*)(wp + (long)nt * 512);
            acc[0][nt] = __builtin_amdgcn_mfma_f32_16x16x32_f16(a0, bfr, acc[0][nt], 0, 0, 0);
            acc[1][nt] = __builtin_amdgcn_mfma_f32_16x16x32_f16(a1, bfr, acc[1][nt], 0, 0, 0);
        }
    }
    // C/D layout: col = lane&15, row = quad*4 + reg
    #pragma unroll
    for (int mt = 0; mt < 2; mt++){
        #pragma unroll
        for (int reg = 0; reg < 4; reg++){
            long r = row0 + mt * 16 + quad * 4 + reg;
            if (r < NN){
                #pragma unroll
                for (int nt = 0; nt < NT; nt++)
                    H2[r * MPH + nt * 16 + l16] = (f16)acc[mt][nt][reg];
            }
        }
    }

    // ---- fused alpha phase ----
    if (threadIdx.x < 128){
        long n = (long)blockIdx.x * 128 + threadIdx.x;
        if (n < NN){
            float s[HH] = {}, d[HH] = {};
            const f16* x = Xh + n * KP;
            for (int k = 0; k < K; k += 4){
                half4 xv = *(const half4*)(x + k);
                float xf0 = (float)xv[0], xf1 = (float)xv[1];
                float xf2 = (float)xv[2], xf3 = (float)xv[3];
                #pragma unroll
                for (int hd = 0; hd < HH; hd++){
                    s[hd] = fmaf(xf0, Was[(k + 0) * HH + hd], s[hd]);
                    s[hd] = fmaf(xf1, Was[(k + 1) * HH + hd], s[hd]);
                    s[hd] = fmaf(xf2, Was[(k + 2) * HH + hd], s[hd]);
                    s[hd] = fmaf(xf3, Was[(k + 3) * HH + hd], s[hd]);
                    d[hd] = fmaf(xf0, Wad[(k + 0) * HH + hd], d[hd]);
                    d[hd] = fmaf(xf1, Wad[(k + 1) * HH + hd], d[hd]);
                    d[hd] = fmaf(xf2, Wad[(k + 2) * HH + hd], d[hd]);
                    d[hd] = fmaf(xf3, Wad[(k + 3) * HH + hd], d[hd]);
                }
            }
            #pragma unroll
            for (int hd = 0; hd < HH; hd++){
                als[n * HH + hd] = s[hd];
                ald[n * HH + hd] = d[hd];
            }
        }
    }
}

// ---------------- softmax m,z per (dst, head), 2x unrolled ----------------
template<int HH>
__global__ void k_mz(const float* __restrict__ als, const float* __restrict__ ald,
                     const int* __restrict__ rowptr, const int* __restrict__ ssrc,
                     float* __restrict__ marr, float* __restrict__ zarr){
    int idx = blockIdx.x * BS + threadIdx.x;
    if (idx >= NN * HH) return;
    int n = idx / HH, hd = idx - n * HH;
    float adv = ald[idx];
    int beg = rowptr[n], end = rowptr[n + 1];
    float m = -1e30f;
    int p = beg;
    for (; p + 2 <= end; p += 2){
        float e0 = als[ssrc[p] * HH + hd] + adv;
        float e1 = als[ssrc[p + 1] * HH + hd] + adv;
        e0 = (e0 >= 0.f) ? e0 : 0.2f * e0;
        e1 = (e1 >= 0.f) ? e1 : 0.2f * e1;
        m = fmaxf(m, fmaxf(e0, e1));
    }
    if (p < end){
        float e = als[ssrc[p] * HH + hd] + adv;
        e = (e >= 0.f) ? e : 0.2f * e;
        m = fmaxf(m, e);
    }
    float z = 0.f;
    p = beg;
    for (; p + 2 <= end; p += 2){
        float e0 = als[ssrc[p] * HH + hd] + adv;
        float e1 = als[ssrc[p + 1] * HH + hd] + adv;
        e0 = (e0 >= 0.f) ? e0 : 0.2f * e0;
        e1 = (e1 >= 0.f) ? e1 : 0.2f * e1;
        z += expf(e0 - m) + expf(e1 - m);
    }
    if (p < end){
        float e = als[ssrc[p] * HH + hd] + adv;
        e = (e >= 0.f) ? e : 0.2f * e;
        z += expf(e - m);
    }
    marr[idx] = m;
    zarr[idx] = z;
}

// ---------------- fused softmax + aggregate, 2x unrolled ----------------
// MPH = H2 row stride (gather width); MPO = output row stride (next layer KP).
template<int HH, int CC, int MPH, int MPO, int VEC, bool O16>
__global__ __launch_bounds__(256) void k_agg_h(const f16* __restrict__ H2,
        const float* __restrict__ als, const float* __restrict__ ald,
        const float* __restrict__ marr, const float* __restrict__ zarr,
        const int* __restrict__ rowptr, const int* __restrict__ ssrc,
        const float* __restrict__ bp, f16* __restrict__ out16,
        float* __restrict__ out32, int MREAL){
    constexpr int TPN = MPO / VEC;
    typedef typename HV<VEC>::type hvec;
    int idx = blockIdx.x * 256 + threadIdx.x;
    if (idx >= NN * TPN) return;
    int n = idx / TPN;
    int q = idx - n * TPN;
    int j0 = q * VEC;
    if constexpr (O16 && (MPO > MPH)){
        if (j0 >= MPH){                     // output pad cols: zero, no gather
            hvec zv = {};
            *(hvec*)(out16 + (long)n * MPO + j0) = zv;
            return;
        }
    }
    int hd = j0 / CC; if (hd > HH - 1) hd = HH - 1;   // H2 pad cols are zero

    float mv   = marr[n * HH + hd];
    float zinv = 1.f / zarr[n * HH + hd];
    float adv  = ald[n * HH + hd];
    int beg = rowptr[n], end = rowptr[n + 1];

    float acc[VEC] = {};
    int p = beg;
    for (; p + 2 <= end; p += 2){
        int s0 = ssrc[p], s1 = ssrc[p + 1];
        float e0 = als[s0 * HH + hd] + adv;
        float e1 = als[s1 * HH + hd] + adv;
        hvec h0 = *(const hvec*)(H2 + (long)s0 * MPH + j0);
        hvec h1 = *(const hvec*)(H2 + (long)s1 * MPH + j0);
        e0 = (e0 >= 0.f) ? e0 : 0.2f * e0;
        e1 = (e1 >= 0.f) ? e1 : 0.2f * e1;
        float ex0 = expf(e0 - mv);
        float ex1 = expf(e1 - mv);
        #pragma unroll
        for (int c = 0; c < VEC; c++){
            acc[c] = fmaf(ex0, (float)h0[c], acc[c]);
            acc[c] = fmaf(ex1, (float)h1[c], acc[c]);
        }
    }
    if (p < end){
        int s = ssrc[p];
        float e = als[s * HH + hd] + adv;
        e = (e >= 0.f) ? e : 0.2f * e;
        float ex = expf(e - mv);
        hvec hv = *(const hvec*)(H2 + (long)s * MPH + j0);
        #pragma unroll
        for (int c = 0; c < VEC; c++)
            acc[c] = fmaf(ex, (float)hv[c], acc[c]);
    }
    if constexpr (O16){
        hvec o;
        #pragma unroll
        for (int c = 0; c < VEC; c++){
            float v = fmaf(acc[c], zinv, bp[j0 + c]);
            o[c] = (f16)((v > 0.f) ? v : 0.f);
        }
        *(hvec*)(out16 + (long)n * MPO + j0) = o;
    } else {
        if (j0 < MREAL){
            #pragma unroll
            for (int c = 0; c < VEC; c++){
                float v = fmaf(acc[c], zinv, bp[j0 + c]);
                out32[(long)n * MREAL + j0 + c] = (v > 0.f) ? v : 0.f;
            }
        }
    }
}

// ---------------- X0 fp32 -> fp16 ----------------
__global__ void k_cvt0(const float* __restrict__ X, f16* __restrict__ Xh){
    long i = (long)blockIdx.x * BS + threadIdx.x;
    if (i >= (long)NN * 8) return;
    float4 v = *(const float4*)(X + i * 4);
    half4 h = { (f16)v.x, (f16)v.y, (f16)v.z, (f16)v.w };
    *(half4*)(Xh + i * 4) = h;
}

// ---------------- layer driver ----------------
template<int K, int M, int KP, int MPH, int MPO, int HH, int CC, int VEC, bool O16>
static void run_layer(const f16* Xh, f16* H2,
                      const f16* Wpk, const float* bp, const float* Was, const float* Wad,
                      float* als, float* ald, float* marr, float* zarr,
                      const int* rowptr, const int* ssrc,
                      f16* Xnext, float* out32, hipStream_t stream){
    constexpr int TPN = MPO / VEC;
    k_gemm_mfma<K, KP, MPH, HH><<<cdiv(NN, 128), 256, 0, stream>>>(
        Xh, Wpk, H2, Was, Wad, als, ald);
    k_mz<HH><<<cdiv((long)NN * HH, BS), BS, 0, stream>>>(als, ald, rowptr, ssrc, marr, zarr);
    k_agg_h<HH, CC, MPH, MPO, VEC, O16><<<cdiv((long)NN * TPN, 256), 256, 0, stream>>>(
        H2, als, ald, marr, zarr, rowptr, ssrc, bp, Xnext, out32, M);
}

extern "C" void kernel_launch(void* const* d_in, const int* in_sizes, int n_in,
                              void* d_out, int out_size, void* d_ws, size_t ws_size,
                              hipStream_t stream){
    const float* x0 = (const float*)d_in[0];
    const int*   ei = (const int*)d_in[1];
    PrepAll pa;
    for (int i = 0; i < 5; i++){
        pa.W[i]  = (const float*)d_in[3 + 4 * i];
        pa.b[i]  = (const float*)d_in[4 + 4 * i];
        pa.as[i] = (const float*)d_in[5 + 4 * i];
        pa.ad[i] = (const float*)d_in[6 + 4 * i];
    }

    char* p = (char*)d_ws;
    auto alloc = [&](size_t bytes) -> char* {
        char* r = p;
        p += (bytes + 255) & ~(size_t)255;
        return r;
    };
    f16*   Xh     = (f16*)alloc((size_t)NN * 256 * 2);
    f16*   H2     = (f16*)alloc((size_t)NN * 256 * 2);
    float* als    = (float*)alloc((size_t)NN * 10 * 4);
    float* ald    = (float*)alloc((size_t)NN * 10 * 4);
    float* marr   = (float*)alloc((size_t)NN * 10 * 4);
    float* zarr   = (float*)alloc((size_t)NN * 10 * 4);
    const int wpkSz[5] = {7680, 32768, 8192, 2048, 512};
    const int mpSz[5]  = {240, 128, 64, 32, 16};
    const int khSz[5]  = {320, 1200, 240, 48, 24};
    for (int i = 0; i < 5; i++){
        pa.Wpk[i] = (f16*)alloc((size_t)wpkSz[i] * 2);
        pa.bp[i]  = (float*)alloc((size_t)mpSz[i] * 4);
        pa.Was[i] = (float*)alloc((size_t)khSz[i] * 4);
        pa.Wad[i] = (float*)alloc((size_t)khSz[i] * 4);
    }
    int*   deg    = (int*)alloc((size_t)NN * 4);
    int*   part   = (int*)alloc((size_t)NN * 4);
    int*   bsum   = (int*)alloc(512 * 4);
    int*   rowptr = (int*)alloc((size_t)(NN + 1) * 4);
    int*   cursor = (int*)alloc((size_t)NN * 4);
    int*   ssrc   = (int*)alloc((size_t)ET * 4);

    // ---- CSR build + prep + cvt ----
    k_prep_all<<<200, 256, 0, stream>>>(pa);
    k_zero_i32<<<cdiv(NN, BS), BS, 0, stream>>>(deg, NN);
    k_deg<<<cdiv(ET, BS), BS, 0, stream>>>(ei, deg);
    int nb = cdiv(NN, BS);
    k_scan1<<<nb, BS, 0, stream>>>(deg, part, bsum, NN);
    k_scan2<<<1, 512, 0, stream>>>(bsum, nb);
    k_scan3<<<cdiv(NN, BS), BS, 0, stream>>>(part, bsum, deg, rowptr, cursor, NN);
    k_fill<<<cdiv(ET, BS), BS, 0, stream>>>(ei, cursor, ssrc);
    k_cvt0<<<cdiv((long)NN * 8, BS), BS, 0, stream>>>(x0, Xh);

    // ---- 5 GAT layers ----
    //         K    M   KP  MPH  MPO  HH  CC VEC O16
    run_layer< 32, 240,  32, 240, 256, 10, 24, 8, true >(Xh, H2, pa.Wpk[0], pa.bp[0],
        pa.Was[0], pa.Wad[0], als, ald, marr, zarr, rowptr, ssrc, Xh, nullptr, stream);
    run_layer<240, 120, 256, 128, 128,  5, 24, 8, true >(Xh, H2, pa.Wpk[1], pa.bp[1],
        pa.Was[1], pa.Wad[1], als, ald, marr, zarr, rowptr, ssrc, Xh, nullptr, stream);
    run_layer<120,  48, 128,  64,  64,  2, 24, 8, true >(Xh, H2, pa.Wpk[2], pa.bp[2],
        pa.Was[2], pa.Wad[2], als, ald, marr, zarr, rowptr, ssrc, Xh, nullptr, stream);
    run_layer< 48,  24,  64,  32,  32,  1, 24, 8, true >(Xh, H2, pa.Wpk[3], pa.bp[3],
        pa.Was[3], pa.Wad[3], als, ald, marr, zarr, rowptr, ssrc, Xh, nullptr, stream);
    run_layer< 24,  12,  32,  16,  16,  1, 12, 4, false>(Xh, H2, pa.Wpk[4], pa.bp[4],
        pa.Was[4], pa.Wad[4], als, ald, marr, zarr, rowptr, ssrc, nullptr, (float*)d_out, stream);
}